// Round 7
// baseline (667.325 us; speedup 1.0000x reference)
//
#include <hip/hip_runtime.h>
#include <hip/hip_bf16.h>

#define N_ROWS 8192
#define NZ 16384           // rows of Z = [An; Bn]
#define DIM 256
#define TAU_INV 2.0f
#define BT 128             // block tile (square)
#define BK 64
#define NTILE 128          // NZ / BT
#define NTRI (NTILE * (NTILE + 1) / 2)   // 8256 upper-tri blocks

typedef float f32x4 __attribute__((ext_vector_type(4)));
typedef short bf16x8 __attribute__((ext_vector_type(8)));

// ---------------------------------------------------------------------------
// Kernel 1: one WAVE per row. L2-normalize z1,z2 rows -> bf16 Zn (An rows
// 0..8191, Bn rows 8192..16383); pos[i] = dot of the QUANTIZED an_i,bn_i
// (matches what the MFMA diagonal would see). Also zeroes S[0..16383].
// ---------------------------------------------------------------------------
__global__ __launch_bounds__(256) void normalize_kernel(
    const float* __restrict__ z1, const float* __restrict__ z2,
    __hip_bfloat16* __restrict__ Zn, float* __restrict__ pos,
    float* __restrict__ Szero)
{
    const int tid = threadIdx.x;
    if (blockIdx.x < 64) Szero[blockIdx.x * 256 + tid] = 0.0f;  // 16384 floats

    const int wave = tid >> 6;
    const int lane = tid & 63;
    const int row = blockIdx.x * 4 + wave;      // 0..8191

    const float4 a = ((const float4*)(z1 + (size_t)row * DIM))[lane];
    const float4 b = ((const float4*)(z2 + (size_t)row * DIM))[lane];

    auto wsum = [&](float v) -> float {
        #pragma unroll
        for (int m = 1; m < 64; m <<= 1) v += __shfl_xor(v, m, 64);
        return v;
    };

    const float na2 = wsum(a.x*a.x + a.y*a.y + a.z*a.z + a.w*a.w);
    const float nb2 = wsum(b.x*b.x + b.y*b.y + b.z*b.z + b.w*b.w);
    const float ia = 1.0f / sqrtf(na2);   // norms ~16; eps never binds
    const float ib = 1.0f / sqrtf(nb2);

    __hip_bfloat16 ah[4] = { __float2bfloat16(a.x*ia), __float2bfloat16(a.y*ia),
                             __float2bfloat16(a.z*ia), __float2bfloat16(a.w*ia) };
    __hip_bfloat16 bh[4] = { __float2bfloat16(b.x*ib), __float2bfloat16(b.y*ib),
                             __float2bfloat16(b.z*ib), __float2bfloat16(b.w*ib) };
    *(ushort4*)(Zn + (size_t)row * DIM + lane * 4) = *(ushort4*)ah;
    *(ushort4*)(Zn + (size_t)(N_ROWS + row) * DIM + lane * 4) = *(ushort4*)bh;

    float qd = 0.0f;
    #pragma unroll
    for (int k = 0; k < 4; ++k)
        qd += __bfloat162float(ah[k]) * __bfloat162float(bh[k]);
    qd = wsum(qd);
    if (lane == 0) pos[row] = qd;
}

// ---------------------------------------------------------------------------
// Kernel 2: symmetric gram of Z, upper triangle, dense triangular grid.
// R5 config (best measured: 102.6 us): block tile 128x128, 4 waves in 2x2,
// wave tile 64x64 (4x4 frags of 16x16x32 bf16), BK=64, 32 KB LDS with
// 16B-group XOR swizzle (0 conflicts measured).
// NEW: __launch_bounds__(256,5) -> <=102 unified regs -> 5 blocks/CU
// (LDS 5x32KB = 160 KiB exactly). Epilogue: atomics straight into S
// (no part array / reduce kernel).
// ---------------------------------------------------------------------------
__global__ __launch_bounds__(256, 5) void gram_kernel(
    const __hip_bfloat16* __restrict__ Z, float* __restrict__ S)
{
    // XCD band remap (8256 = 8 * 1032), then triangular decode.
    const int bid = (blockIdx.x & 7) * (NTRI / 8) + (blockIdx.x >> 3);
    // P(ti) = ti*(257-ti)/2; find ti with P(ti) <= bid < P(ti+1)
    int ti = (int)((257.0f - sqrtf(66049.0f - 8.0f * (float)bid)) * 0.5f);
    ti = ti < 0 ? 0 : (ti > 127 ? 127 : ti);
    while (ti * (257 - ti) / 2 > bid) --ti;
    while ((ti + 1) * (256 - ti) / 2 <= bid) ++ti;
    const int tj = ti + (bid - ti * (257 - ti) / 2);
    const bool diag = (ti == tj);

    __shared__ __hip_bfloat16 As[BT * BK];   // 16 KB
    __shared__ __hip_bfloat16 Bs[BT * BK];   // 16 KB

    const int tid  = threadIdx.x;
    const int wave = tid >> 6;
    const int lane = tid & 63;
    const int wr = wave >> 1;           // row half (0..1)
    const int wc = wave & 1;            // col half (0..1)
    const int lm = lane & 15;
    const int lq = lane >> 4;

    const int rowBase = ti * BT;
    const int colBase = tj * BT;

    // staging: chunk = 8 rows x 8 groups of 16B (1 KB); LDS[r][g]=glob[r][g^(r&7)]
    const int srow  = lane >> 3;                // 0..7
    const int sgcol = ((lane & 7) ^ srow) << 3; // swizzled elem offset in row

    // pointer-increment staging bases (trim live regs / VALU)
    const __hip_bfloat16* gA =
        Z + (size_t)(rowBase + wave * 32 + srow) * DIM + sgcol;
    const __hip_bfloat16* gB =
        Z + (size_t)(colBase + wave * 32 + srow) * DIM + sgcol;

    f32x4 acc[4][4] = {};

    for (int k0 = 0; k0 < DIM; k0 += BK) {
        if (k0) __syncthreads();        // protect LDS being read (prev iter)
        #pragma unroll
        for (int c = 0; c < 4; ++c) {   // 16 chunks each, 4 per wave
            const int ch = wave * 4 + c;
            __builtin_amdgcn_global_load_lds(
                (const __attribute__((address_space(1))) void*)(gA + c * 8 * DIM),
                (__attribute__((address_space(3))) void*)(As + ch * 512),
                16, 0, 0);
            __builtin_amdgcn_global_load_lds(
                (const __attribute__((address_space(1))) void*)(gB + c * 8 * DIM),
                (__attribute__((address_space(3))) void*)(Bs + ch * 512),
                16, 0, 0);
        }
        gA += BK; gB += BK;
        __syncthreads();

        #pragma unroll
        for (int kk = 0; kk < BK; kk += 32) {
            const int g = (kk >> 3) + lq;       // 16B group index
            bf16x8 af[4], bf[4];
            #pragma unroll
            for (int f = 0; f < 4; ++f) {
                const int ra = wr * 64 + f * 16 + lm;
                const int rb = wc * 64 + f * 16 + lm;
                af[f] = *(const bf16x8*)(As + ra * BK + ((g ^ (ra & 7)) << 3));
                bf[f] = *(const bf16x8*)(Bs + rb * BK + ((g ^ (rb & 7)) << 3));
            }
            #pragma unroll
            for (int fr = 0; fr < 4; ++fr)
                #pragma unroll
                for (int fc = 0; fc < 4; ++fc)
                    acc[fr][fc] = __builtin_amdgcn_mfma_f32_16x16x32_bf16(
                        af[fr], bf[fc], acc[fr][fc], 0, 0, 0);
        }
    }
    // epilogue is LDS-free: no trailing barrier

    // exp(2c) = exp2(c * 2*log2(e)); C/D layout: col=lane&15, row=lq*4+reg
    const float SC = 2.8853900817779268f;
    #pragma unroll
    for (int fr = 0; fr < 4; ++fr)
        #pragma unroll
        for (int fc = 0; fc < 4; ++fc)
            #pragma unroll
            for (int r = 0; r < 4; ++r)
                acc[fr][fc][r] = exp2f(acc[fr][fc][r] * SC);

    if (diag) {   // zero at-or-below-diagonal (each pair counted once)
        #pragma unroll
        for (int fr = 0; fr < 4; ++fr) {
            const int gi = wr * 64 + fr * 16 + lq * 4;
            #pragma unroll
            for (int fc = 0; fc < 4; ++fc) {
                const int gj = wc * 64 + fc * 16 + lm;
                #pragma unroll
                for (int r = 0; r < 4; ++r)
                    if (gj <= gi + r) acc[fr][fc][r] = 0.0f;
            }
        }
    }

    // row partials over this wave's 64 cols -> atomics (device-scope default)
    #pragma unroll
    for (int fr = 0; fr < 4; ++fr)
        #pragma unroll
        for (int r = 0; r < 4; ++r) {
            float s = acc[fr][0][r] + acc[fr][1][r] + acc[fr][2][r] + acc[fr][3][r];
            s += __shfl_xor(s, 1, 64);
            s += __shfl_xor(s, 2, 64);
            s += __shfl_xor(s, 4, 64);
            s += __shfl_xor(s, 8, 64);
            if (lm == 0)
                atomicAdd(&S[rowBase + wr * 64 + fr * 16 + lq * 4 + r], s);
        }
    // col partials over this wave's 64 rows (symmetry: colsum feeds S too)
    #pragma unroll
    for (int fc = 0; fc < 4; ++fc) {
        float s = 0.0f;
        #pragma unroll
        for (int fr = 0; fr < 4; ++fr)
            #pragma unroll
            for (int r = 0; r < 4; ++r) s += acc[fr][fc][r];
        s += __shfl_xor(s, 16, 64);
        s += __shfl_xor(s, 32, 64);
        if (lq == 0)
            atomicAdd(&S[colBase + wc * 64 + fc * 16 + lm], s);
    }
}

// ---------------------------------------------------------------------------
// Kernel 3: per-row loss + mean. S holds diag-excluded sums:
// den1 = S[i], den2 = S[N+i].
// ---------------------------------------------------------------------------
__global__ __launch_bounds__(256) void loss_kernel(
    const float* __restrict__ S, const float* __restrict__ pos,
    float* __restrict__ out)
{
    const int i = blockIdx.x * 256 + threadIdx.x;
    float v = 0.5f * (logf(S[i]) + logf(S[N_ROWS + i])) - TAU_INV * pos[i];

    __shared__ float red[4];
    #pragma unroll
    for (int m = 1; m < 64; m <<= 1) v += __shfl_xor(v, m, 64);
    if ((threadIdx.x & 63) == 0) red[threadIdx.x >> 6] = v;
    __syncthreads();
    if (threadIdx.x == 0)
        atomicAdd(out, (red[0] + red[1] + red[2] + red[3]) * (1.0f / N_ROWS));
}

// ---------------------------------------------------------------------------
extern "C" void kernel_launch(void* const* d_in, const int* in_sizes, int n_in,
                              void* d_out, int out_size, void* d_ws, size_t ws_size,
                              hipStream_t stream)
{
    const float* z1 = (const float*)d_in[0];
    const float* z2 = (const float*)d_in[1];
    float* out = (float*)d_out;

    char* ws = (char*)d_ws;
    __hip_bfloat16* Zn = (__hip_bfloat16*)ws;            // 8 MB
    float* pos = (float*)(ws + 8388608);                 // 32 KB
    float* S   = (float*)(ws + 8421376);                 // 64 KB

    hipMemsetAsync(out, 0, sizeof(float), stream);
    // normalize also zeroes S (gram's atomic accumulator)
    normalize_kernel<<<N_ROWS / 4, 256, 0, stream>>>(z1, z2, Zn, pos, S);

    gram_kernel<<<NTRI, 256, 0, stream>>>(Zn, S);

    loss_kernel<<<N_ROWS / 256, 256, 0, stream>>>(S, pos, out);
}

// Round 9
// 280.965 us; speedup vs baseline: 2.3751x; 2.3751x over previous
//
#include <hip/hip_runtime.h>
#include <hip/hip_bf16.h>
#include <hip/hip_fp8.h>

#define N_ROWS 8192
#define NZ 16384           // rows of Z = [An; Bn]
#define DIM 256
#define TAU_INV 2.0f
#define BT 128             // block tile (square)
#define BK 64
#define NTILE 128          // NZ / BT
#define NTRI (NTILE * (NTILE + 1) / 2)   // 8256 upper-tri blocks

typedef float f32x4 __attribute__((ext_vector_type(4)));
typedef long fp8x8;        // 8 fp8 values in 2 VGPRs (i64 MFMA operand)

// ---------------------------------------------------------------------------
// Kernel 1: one WAVE per row. L2-normalize z1,z2 rows, scale by 16, quantize
// to OCP fp8 e4m3 -> Z8 (An rows 0..8191, Bn rows 8192..16383).
// pos[i] = (1/256) * dot(fp8(an*16), fp8(bn*16)) from the QUANTIZED values
// (matches what the MFMA sees). Also zeroes S[0..16383].
// ---------------------------------------------------------------------------
__global__ __launch_bounds__(256) void normalize_kernel(
    const float* __restrict__ z1, const float* __restrict__ z2,
    unsigned char* __restrict__ Z8, float* __restrict__ pos,
    float* __restrict__ Szero)
{
    const int tid = threadIdx.x;
    if (blockIdx.x < 64) Szero[blockIdx.x * 256 + tid] = 0.0f;  // 16384 floats

    const int wave = tid >> 6;
    const int lane = tid & 63;
    const int row = blockIdx.x * 4 + wave;      // 0..8191

    const float4 a = ((const float4*)(z1 + (size_t)row * DIM))[lane];
    const float4 b = ((const float4*)(z2 + (size_t)row * DIM))[lane];

    auto wsum = [&](float v) -> float {
        #pragma unroll
        for (int m = 1; m < 64; m <<= 1) v += __shfl_xor(v, m, 64);
        return v;
    };

    const float na2 = wsum(a.x*a.x + a.y*a.y + a.z*a.z + a.w*a.w);
    const float nb2 = wsum(b.x*b.x + b.y*b.y + b.z*b.z + b.w*b.w);
    const float sa = 16.0f / sqrtf(na2);   // normalize * 16 (fp8 range use)
    const float sb = 16.0f / sqrtf(nb2);

    const float av[4] = {a.x*sa, a.y*sa, a.z*sa, a.w*sa};
    const float bv[4] = {b.x*sb, b.y*sb, b.z*sb, b.w*sb};
    unsigned char pa[4], pb[4];
    float qd = 0.0f;
    #pragma unroll
    for (int k = 0; k < 4; ++k) {
        __hip_fp8_e4m3 qa(av[k]);
        __hip_fp8_e4m3 qb(bv[k]);
        pa[k] = qa.__x; pb[k] = qb.__x;
        qd += float(qa) * float(qb);
    }
    *(uchar4*)(Z8 + (size_t)row * DIM + lane * 4) = *(uchar4*)pa;
    *(uchar4*)(Z8 + (size_t)(N_ROWS + row) * DIM + lane * 4) = *(uchar4*)pb;

    qd = wsum(qd);
    if (lane == 0) pos[row] = qd * 0.00390625f;   // /256 -> quantized sim
}

// ---------------------------------------------------------------------------
// Kernel 2: symmetric gram of Z8 (fp8), upper triangle, dense triangular grid.
// Block tile 128x128, 4 waves in 2x2, wave tile 64x64 (4x4 frags of
// mfma_f32_16x16x32_fp8_fp8 — bf16 rate, HALF the bytes of R5 everywhere).
// BK=64 -> A,B tiles 8 KB each. __launch_bounds__(256,4): 128-reg cap is the
// proven no-spill tier (R7's (256,5) spilled -> 1.7 GB scratch traffic).
// LDS dest of global_load_lds is the WAVE-UNIFORM chunk base (HW adds
// lane*16) — R8 passed a divergent pointer; fixed here.
// Swizzle: LDS[r][G16] = glob[r][G16 ^ ((r>>1)&3)] on 16B granules; the 8B
// reads then see only 2-way bank aliasing (free, m136).
// ---------------------------------------------------------------------------
__global__ __launch_bounds__(256, 4) void gram_kernel(
    const unsigned char* __restrict__ Z, float* __restrict__ S)
{
    // XCD band remap (8256 = 8 * 1032), then triangular decode.
    const int bid = (blockIdx.x & 7) * (NTRI / 8) + (blockIdx.x >> 3);
    int ti = (int)((257.0f - sqrtf(66049.0f - 8.0f * (float)bid)) * 0.5f);
    ti = ti < 0 ? 0 : (ti > 127 ? 127 : ti);
    while (ti * (257 - ti) / 2 > bid) --ti;
    while ((ti + 1) * (256 - ti) / 2 <= bid) ++ti;
    const int tj = ti + (bid - ti * (257 - ti) / 2);
    const bool diag = (ti == tj);

    __shared__ unsigned char As[BT * BK];   // 8 KB
    __shared__ unsigned char Bs[BT * BK];   // 8 KB

    const int tid  = threadIdx.x;
    const int wave = tid >> 6;
    const int lane = tid & 63;
    const int wr = wave >> 1;           // row half (0..1)
    const int wc = wave & 1;            // col half (0..1)
    const int lm = lane & 15;
    const int lq = lane >> 4;

    const int rowBase = ti * BT;
    const int colBase = tj * BT;

    // staging: one instr = 64 lanes x 16B = 16 rows x 4 granules; wave w
    // stages rows [32w, 32w+32) of A and B as 2 chunks each.
    // lane = srow*4 + sg; global granule fetched = sg ^ ((row>>1)&3).
    const int srow = lane >> 2;                 // 0..15
    const int sg   = lane & 3;                  // granule slot
    const int r0   = wave * 32 + srow;
    const int f0   = (r0 >> 1) & 3;             // swizzle key (rows step 16/chunk)
    const int sgc  = (sg ^ f0) << 4;            // swizzled byte offset in row
    const unsigned char* gA = Z + (size_t)(rowBase + r0) * DIM + sgc;
    const unsigned char* gB = Z + (size_t)(colBase + r0) * DIM + sgc;

    const int flm = (lm >> 1) & 3;              // read-side swizzle key

    f32x4 acc[4][4] = {};

    for (int k0 = 0; k0 < DIM; k0 += BK) {
        if (k0) __syncthreads();        // protect LDS being read (prev iter)
        #pragma unroll
        for (int c = 0; c < 2; ++c) {   // 8 chunks each, 2 per wave
            const int ch = wave * 2 + c;     // wave-uniform
            __builtin_amdgcn_global_load_lds(
                (const __attribute__((address_space(1))) void*)(gA + k0 + c * 16 * DIM),
                (__attribute__((address_space(3))) void*)(As + ch * 1024),
                16, 0, 0);
            __builtin_amdgcn_global_load_lds(
                (const __attribute__((address_space(1))) void*)(gB + k0 + c * 16 * DIM),
                (__attribute__((address_space(3))) void*)(Bs + ch * 1024),
                16, 0, 0);
        }
        __syncthreads();

        #pragma unroll
        for (int kk = 0; kk < BK; kk += 32) {
            const int gg  = lq + (kk >> 3);     // 8B-group index 0..7
            const int G   = gg >> 1;            // 16B granule
            const int sub = (gg & 1) << 3;      // byte offset within granule
            const int goff = ((G ^ flm) << 4) + sub;
            fp8x8 af[4], bf[4];
            #pragma unroll
            for (int f = 0; f < 4; ++f) {
                const int ra = wr * 64 + f * 16 + lm;
                const int rb = wc * 64 + f * 16 + lm;
                af[f] = *(const fp8x8*)(As + ra * BK + goff);
                bf[f] = *(const fp8x8*)(Bs + rb * BK + goff);
            }
            #pragma unroll
            for (int fr = 0; fr < 4; ++fr)
                #pragma unroll
                for (int fc = 0; fc < 4; ++fc)
                    acc[fr][fc] = __builtin_amdgcn_mfma_f32_16x16x32_fp8_fp8(
                        af[fr], bf[fc], acc[fr][fc], 0, 0, 0);
        }
    }
    // epilogue is LDS-free: no trailing barrier

    // dot = 256*sim; exp(2*sim) = exp2(dot * 2*log2(e)/256)
    const float SC = 2.8853900817779268f / 256.0f;
    #pragma unroll
    for (int fr = 0; fr < 4; ++fr)
        #pragma unroll
        for (int fc = 0; fc < 4; ++fc)
            #pragma unroll
            for (int r = 0; r < 4; ++r)
                acc[fr][fc][r] = exp2f(acc[fr][fc][r] * SC);

    if (diag) {   // zero at-or-below-diagonal (each pair counted once)
        #pragma unroll
        for (int fr = 0; fr < 4; ++fr) {
            const int gi = wr * 64 + fr * 16 + lq * 4;
            #pragma unroll
            for (int fc = 0; fc < 4; ++fc) {
                const int gj = wc * 64 + fc * 16 + lm;
                #pragma unroll
                for (int r = 0; r < 4; ++r)
                    if (gj <= gi + r) acc[fr][fc][r] = 0.0f;
            }
        }
    }

    // row partials over this wave's 64 cols (C/D: col=lane&15, row=lq*4+reg)
    #pragma unroll
    for (int fr = 0; fr < 4; ++fr)
        #pragma unroll
        for (int r = 0; r < 4; ++r) {
            float s = acc[fr][0][r] + acc[fr][1][r] + acc[fr][2][r] + acc[fr][3][r];
            s += __shfl_xor(s, 1, 64);
            s += __shfl_xor(s, 2, 64);
            s += __shfl_xor(s, 4, 64);
            s += __shfl_xor(s, 8, 64);
            if (lm == 0)
                atomicAdd(&S[rowBase + wr * 64 + fr * 16 + lq * 4 + r], s);
        }
    // col partials over this wave's 64 rows (symmetry: colsum feeds S too)
    #pragma unroll
    for (int fc = 0; fc < 4; ++fc) {
        float s = 0.0f;
        #pragma unroll
        for (int fr = 0; fr < 4; ++fr)
            #pragma unroll
            for (int r = 0; r < 4; ++r) s += acc[fr][fc][r];
        s += __shfl_xor(s, 16, 64);
        s += __shfl_xor(s, 32, 64);
        if (lq == 0)
            atomicAdd(&S[colBase + wc * 64 + fc * 16 + lm], s);
    }
}

// ---------------------------------------------------------------------------
// Kernel 3: per-row loss + mean. S holds diag-excluded sums; pos is the
// quantized cross-sim. den1 = S[i], den2 = S[N+i].
// ---------------------------------------------------------------------------
__global__ __launch_bounds__(256) void loss_kernel(
    const float* __restrict__ S, const float* __restrict__ pos,
    float* __restrict__ out)
{
    const int i = blockIdx.x * 256 + threadIdx.x;
    float v = 0.5f * (logf(S[i]) + logf(S[N_ROWS + i])) - TAU_INV * pos[i];

    __shared__ float red[4];
    #pragma unroll
    for (int m = 1; m < 64; m <<= 1) v += __shfl_xor(v, m, 64);
    if ((threadIdx.x & 63) == 0) red[threadIdx.x >> 6] = v;
    __syncthreads();
    if (threadIdx.x == 0)
        atomicAdd(out, (red[0] + red[1] + red[2] + red[3]) * (1.0f / N_ROWS));
}

// ---------------------------------------------------------------------------
extern "C" void kernel_launch(void* const* d_in, const int* in_sizes, int n_in,
                              void* d_out, int out_size, void* d_ws, size_t ws_size,
                              hipStream_t stream)
{
    const float* z1 = (const float*)d_in[0];
    const float* z2 = (const float*)d_in[1];
    float* out = (float*)d_out;

    char* ws = (char*)d_ws;
    unsigned char* Z8 = (unsigned char*)ws;              // 16384*256 = 4 MB
    float* pos = (float*)(ws + 4194304);                 // 32 KB
    float* S   = (float*)(ws + 4227072);                 // 64 KB

    hipMemsetAsync(out, 0, sizeof(float), stream);
    // normalize also zeroes S (gram's atomic accumulator)
    normalize_kernel<<<N_ROWS / 4, 256, 0, stream>>>(z1, z2, Z8, pos, S);

    gram_kernel<<<NTRI, 256, 0, stream>>>(Z8, S);

    loss_kernel<<<N_ROWS / 256, 256, 0, stream>>>(S, pos, out);
}

// Round 10
// 179.755 us; speedup vs baseline: 3.7124x; 1.5630x over previous
//
#include <hip/hip_runtime.h>
#include <hip/hip_bf16.h>
#include <hip/hip_fp8.h>

#define N_ROWS 8192
#define NZ 16384           // rows of Z = [An; Bn]
#define DIM 256
#define TAU_INV 2.0f
#define BT 128             // block tile (square)
#define BK 64
#define NTILE 128          // NZ / BT
#define NTRI (NTILE * (NTILE + 1) / 2)   // 8256 upper-tri blocks
#define NCHUNK 16

typedef float f32x4 __attribute__((ext_vector_type(4)));
typedef long fp8x8;        // 8 fp8 values in 2 VGPRs (i64 MFMA operand)

// ---------------------------------------------------------------------------
// Kernel 1: one WAVE per row. L2-normalize z1,z2 rows, scale by 16, quantize
// to OCP fp8 e4m3 -> Z8 (An rows 0..8191, Bn rows 8192..16383).
// pos[i] = (1/256)*dot(fp8(an*16), fp8(bn*16)) from the QUANTIZED values.
// Also zeroes Szero[0..16383] (atomic-fallback accumulator only).
// ---------------------------------------------------------------------------
__global__ __launch_bounds__(256) void normalize_kernel(
    const float* __restrict__ z1, const float* __restrict__ z2,
    unsigned char* __restrict__ Z8, float* __restrict__ pos,
    float* __restrict__ Szero)
{
    const int tid = threadIdx.x;
    if (blockIdx.x < 64) Szero[blockIdx.x * 256 + tid] = 0.0f;

    const int wave = tid >> 6;
    const int lane = tid & 63;
    const int row = blockIdx.x * 4 + wave;      // 0..8191

    const float4 a = ((const float4*)(z1 + (size_t)row * DIM))[lane];
    const float4 b = ((const float4*)(z2 + (size_t)row * DIM))[lane];

    auto wsum = [&](float v) -> float {
        #pragma unroll
        for (int m = 1; m < 64; m <<= 1) v += __shfl_xor(v, m, 64);
        return v;
    };

    const float na2 = wsum(a.x*a.x + a.y*a.y + a.z*a.z + a.w*a.w);
    const float nb2 = wsum(b.x*b.x + b.y*b.y + b.z*b.z + b.w*b.w);
    const float sa = 16.0f / sqrtf(na2);   // normalize * 16 (fp8 range use)
    const float sb = 16.0f / sqrtf(nb2);

    const float av[4] = {a.x*sa, a.y*sa, a.z*sa, a.w*sa};
    const float bv[4] = {b.x*sb, b.y*sb, b.z*sb, b.w*sb};
    unsigned char pa[4], pb[4];
    float qd = 0.0f;
    #pragma unroll
    for (int k = 0; k < 4; ++k) {
        __hip_fp8_e4m3 qa(av[k]);
        __hip_fp8_e4m3 qb(bv[k]);
        pa[k] = qa.__x; pb[k] = qb.__x;
        qd += float(qa) * float(qb);
    }
    *(uchar4*)(Z8 + (size_t)row * DIM + lane * 4) = *(uchar4*)pa;
    *(uchar4*)(Z8 + (size_t)(N_ROWS + row) * DIM + lane * 4) = *(uchar4*)pb;

    qd = wsum(qd);
    if (lane == 0) pos[row] = qd * 0.00390625f;   // /256 -> quantized sim
}

// ---------------------------------------------------------------------------
// Kernel 2: symmetric fp8 gram of Z8, upper triangle, dense triangular grid.
// Block tile 128x128, 4 waves 2x2, wave tile 64x64 (4x4 frags of
// mfma_f32_16x16x32_fp8_fp8 — bf16 rate, half the bytes).
// LDS swizzle at 8B-group granularity: LDS[r][p] = glob[r][p ^ ((r>>1)&7)],
// enabled by WIDTH=4 staging (4B lane chunks). b64 frag reads then have each
// 16-lane quad covering all 32 banks exactly once -> zero conflicts.
// __launch_bounds__(256,4): 128-reg no-spill tier (R7 lesson).
// Epilogue: exp2, diag mask, 512 coalesced part floats per block (NO atomics
// — R9's 4.2M hot atomics cost ~150 us).
// ---------------------------------------------------------------------------
template <bool TWO_STAGE>
__global__ __launch_bounds__(256, 4) void gram_kernel(
    const unsigned char* __restrict__ Z,
    float* __restrict__ part, float* __restrict__ S)
{
    // XCD band remap (8256 = 8 * 1032), then triangular decode.
    const int bid = (blockIdx.x & 7) * (NTRI / 8) + (blockIdx.x >> 3);
    int ti = (int)((257.0f - sqrtf(66049.0f - 8.0f * (float)bid)) * 0.5f);
    ti = ti < 0 ? 0 : (ti > 127 ? 127 : ti);
    while (ti * (257 - ti) / 2 > bid) --ti;
    while ((ti + 1) * (256 - ti) / 2 <= bid) ++ti;
    const int tj = ti + (bid - ti * (257 - ti) / 2);
    const bool diag = (ti == tj);

    __shared__ unsigned char As[BT * BK];   // 8 KB
    __shared__ unsigned char Bs[BT * BK];   // 8 KB

    const int tid  = threadIdx.x;
    const int wave = tid >> 6;
    const int lane = tid & 63;
    const int wr = wave >> 1;           // row half (0..1)
    const int wc = wave & 1;            // col half (0..1)
    const int lm = lane & 15;
    const int lq = lane >> 4;

    const int rowBase = ti * BT;
    const int colBase = tj * BT;

    // width-4 staging geometry: one instr = 64 lanes x 4B = 4 rows x 64B.
    // lane -> row l4 = lane>>4, 8B-group p8 = (lane>>1)&7, half h4 = 4*(lane&1).
    // Global group fetched for LDS pos p8 of row gr: p8 ^ ((gr>>1)&7).
    const int l4 = lane >> 4;
    const int p8 = (lane >> 1) & 7;
    const int h4 = (lane & 1) << 2;

    f32x4 acc[4][4] = {};

    for (int k0 = 0; k0 < DIM; k0 += BK) {
        if (k0) __syncthreads();        // protect LDS being read (prev iter)
        #pragma unroll
        for (int c = 0; c < 8; ++c) {   // 32 chunks each, 8 per wave
            const int ch = wave * 8 + c;            // wave-uniform
            const int gr = ch * 4 + l4;             // tile row (per-lane)
            const int off = ((p8 ^ ((gr >> 1) & 7)) << 3) + h4;
            const unsigned char* ga = Z + (size_t)(rowBase + gr) * DIM + k0 + off;
            const unsigned char* gb = Z + (size_t)(colBase + gr) * DIM + k0 + off;
            __builtin_amdgcn_global_load_lds(
                (const __attribute__((address_space(1))) void*)ga,
                (__attribute__((address_space(3))) void*)(As + ch * 256),
                4, 0, 0);
            __builtin_amdgcn_global_load_lds(
                (const __attribute__((address_space(1))) void*)gb,
                (__attribute__((address_space(3))) void*)(Bs + ch * 256),
                4, 0, 0);
        }
        __syncthreads();

        #pragma unroll
        for (int kk = 0; kk < 2; ++kk) {            // K halves of BK
            fp8x8 af[4], bf[4];
            #pragma unroll
            for (int f = 0; f < 4; ++f) {
                const int ra = wr * 64 + f * 16 + lm;
                const int rb = wc * 64 + f * 16 + lm;
                const int gg = kk * 4 + lq;         // global 8B-group 0..7
                af[f] = *(const fp8x8*)(As + ra * BK + ((gg ^ (lm >> 1)) << 3));
                bf[f] = *(const fp8x8*)(Bs + rb * BK + ((gg ^ (lm >> 1)) << 3));
            }
            #pragma unroll
            for (int fr = 0; fr < 4; ++fr)
                #pragma unroll
                for (int fc = 0; fc < 4; ++fc)
                    acc[fr][fc] = __builtin_amdgcn_mfma_f32_16x16x32_fp8_fp8(
                        af[fr], bf[fc], acc[fr][fc], 0, 0, 0);
        }
    }
    // epilogue is LDS-free: no trailing barrier

    // dot = 256*sim; exp(2*sim) = exp2(dot * 2*log2(e)/256)
    const float SC = 2.8853900817779268f / 256.0f;
    #pragma unroll
    for (int fr = 0; fr < 4; ++fr)
        #pragma unroll
        for (int fc = 0; fc < 4; ++fc)
            #pragma unroll
            for (int r = 0; r < 4; ++r)
                acc[fr][fc][r] = exp2f(acc[fr][fc][r] * SC);

    if (diag) {   // zero at-or-below-diagonal (each pair counted once)
        #pragma unroll
        for (int fr = 0; fr < 4; ++fr) {
            const int gi = wr * 64 + fr * 16 + lq * 4;
            #pragma unroll
            for (int fc = 0; fc < 4; ++fc) {
                const int gj = wc * 64 + fc * 16 + lm;
                #pragma unroll
                for (int r = 0; r < 4; ++r)
                    if (gj <= gi + r) acc[fr][fc][r] = 0.0f;
            }
        }
    }

    float* dst = TWO_STAGE ? (part + (size_t)bid * 512) : nullptr;

    // row partials over this wave's 64 cols (C/D: col=lane&15, row=lq*4+reg)
    #pragma unroll
    for (int fr = 0; fr < 4; ++fr)
        #pragma unroll
        for (int r = 0; r < 4; ++r) {
            float s = acc[fr][0][r] + acc[fr][1][r] + acc[fr][2][r] + acc[fr][3][r];
            s += __shfl_xor(s, 1, 64);
            s += __shfl_xor(s, 2, 64);
            s += __shfl_xor(s, 4, 64);
            s += __shfl_xor(s, 8, 64);
            if (lm == 0) {
                const int rr = wr * 64 + fr * 16 + lq * 4 + r;
                if (TWO_STAGE) dst[wc * 128 + rr] = s;
                else atomicAdd(&S[rowBase + rr], s);
            }
        }
    // col partials over this wave's 64 rows (symmetry: colsum feeds S too)
    #pragma unroll
    for (int fc = 0; fc < 4; ++fc) {
        float s = 0.0f;
        #pragma unroll
        for (int fr = 0; fr < 4; ++fr)
            #pragma unroll
            for (int r = 0; r < 4; ++r) s += acc[fr][fc][r];
        s += __shfl_xor(s, 16, 64);
        s += __shfl_xor(s, 32, 64);
        if (lq == 0) {
            const int cc = wc * 64 + fc * 16 + lm;
            if (TWO_STAGE) dst[256 + wr * 128 + cc] = s;
            else atomicAdd(&S[colBase + cc], s);
        }
    }
}

// ---------------------------------------------------------------------------
// Kernel 3: parallel partial gather. grid (NZ/256, NCHUNK). Each Z-row has
// exactly 258 strips: row-side blocks (tr,tj) tj=tr..127 (slots {0,128}+rr),
// col-side blocks (ti,tr) ti=0..tr (slots 256+{0,128}+rr). All coalesced.
// Also zeroes out[0] (replaces the memset node).
// ---------------------------------------------------------------------------
__global__ __launch_bounds__(256) void reduce_kernel(
    const float* __restrict__ part, float* __restrict__ S2,
    float* __restrict__ out)
{
    const int chunk = blockIdx.y;
    const int tid = threadIdx.x;
    const int r = blockIdx.x * 256 + tid;       // Z row
    const int tr = r >> 7, rr = r & 127;
    const int baseRow = tr * (257 - tr) / 2;    // bid of (tr,tr)
    const int cntRow = 2 * (128 - tr);

    if (chunk == 0 && r == 0) out[0] = 0.0f;

    float s = 0.0f;
    for (int m = chunk; m < 258; m += NCHUNK) {
        size_t addr;
        if (m < cntRow) {
            const int bb = baseRow + (m >> 1);               // tj = tr + m/2
            addr = (size_t)bb * 512 + (m & 1) * 128 + rr;
        } else {
            const int m2 = m - cntRow;
            const int tiq = m2 >> 1;                          // ti = 0..tr
            const int bb = tiq * (257 - tiq) / 2 + (tr - tiq);
            addr = (size_t)bb * 512 + 256 + (m2 & 1) * 128 + rr;
        }
        s += part[addr];
    }
    S2[(size_t)chunk * NZ + r] = s;
}

// ---------------------------------------------------------------------------
// Kernel 4: loss + mean (two-stage path).
// ---------------------------------------------------------------------------
__global__ __launch_bounds__(256) void loss2_kernel(
    const float* __restrict__ S2, const float* __restrict__ pos,
    float* __restrict__ out)
{
    const int i = blockIdx.x * 256 + threadIdx.x;
    float den1 = 0.0f, den2 = 0.0f;
    #pragma unroll
    for (int c = 0; c < NCHUNK; ++c) {
        den1 += S2[(size_t)c * NZ + i];
        den2 += S2[(size_t)c * NZ + N_ROWS + i];
    }
    float v = 0.5f * (logf(den1) + logf(den2)) - TAU_INV * pos[i];

    __shared__ float red[4];
    #pragma unroll
    for (int m = 1; m < 64; m <<= 1) v += __shfl_xor(v, m, 64);
    if ((threadIdx.x & 63) == 0) red[threadIdx.x >> 6] = v;
    __syncthreads();
    if (threadIdx.x == 0)
        atomicAdd(out, (red[0] + red[1] + red[2] + red[3]) * (1.0f / N_ROWS));
}

// Fallback loss (atomic path): S holds diag-excluded sums directly.
__global__ __launch_bounds__(256) void loss_kernel(
    const float* __restrict__ S, const float* __restrict__ pos,
    float* __restrict__ out)
{
    const int i = blockIdx.x * 256 + threadIdx.x;
    float v = 0.5f * (logf(S[i]) + logf(S[N_ROWS + i])) - TAU_INV * pos[i];

    __shared__ float red[4];
    #pragma unroll
    for (int m = 1; m < 64; m <<= 1) v += __shfl_xor(v, m, 64);
    if ((threadIdx.x & 63) == 0) red[threadIdx.x >> 6] = v;
    __syncthreads();
    if (threadIdx.x == 0)
        atomicAdd(out, (red[0] + red[1] + red[2] + red[3]) * (1.0f / N_ROWS));
}

// ---------------------------------------------------------------------------
extern "C" void kernel_launch(void* const* d_in, const int* in_sizes, int n_in,
                              void* d_out, int out_size, void* d_ws, size_t ws_size,
                              hipStream_t stream)
{
    const float* z1 = (const float*)d_in[0];
    const float* z2 = (const float*)d_in[1];
    float* out = (float*)d_out;

    char* ws = (char*)d_ws;
    unsigned char* Z8 = (unsigned char*)ws;              // 16384*256 = 4 MB
    float* pos  = (float*)(ws + 4194304);                // 32 KB
    float* S2   = (float*)(ws + 4227072);                // 16*16384*4 = 1 MB
    float* part = (float*)(ws + 5275648);                // 8256*512*4 = 16.9 MB
    const size_t need = 5275648 + (size_t)NTRI * 512 * 4;

    // normalize also zeroes S2[0..16383] (atomic-fallback accumulator)
    normalize_kernel<<<N_ROWS / 4, 256, 0, stream>>>(z1, z2, Z8, pos, S2);

    if (ws_size >= need) {
        gram_kernel<true><<<NTRI, 256, 0, stream>>>(Z8, part, nullptr);
        dim3 rg(NZ / 256, NCHUNK);
        reduce_kernel<<<rg, 256, 0, stream>>>(part, S2, out);   // zeroes out
        loss2_kernel<<<N_ROWS / 256, 256, 0, stream>>>(S2, pos, out);
    } else {
        hipMemsetAsync(out, 0, sizeof(float), stream);
        gram_kernel<false><<<NTRI, 256, 0, stream>>>(Z8, nullptr, S2);
        loss_kernel<<<N_ROWS / 256, 256, 0, stream>>>(S2, pos, out);
    }
}